// Round 4
// baseline (171.062 us; speedup 1.0000x reference)
//
#include <hip/hip_runtime.h>

#define B_    4
#define L_    2048
#define DIN   256
#define E_    16
#define M_    768
#define ROWS  (L_ + 1)      // 2049 (cls + L)
#define NTOK  (B_ * L_)     // 8192

// ---------------------------------------------------------------------------
// Kernel A: bucket unmasked tokens by expert id.
// ws layout: int counts[16]; int bucket[16][NTOK]
// ---------------------------------------------------------------------------
__global__ void bucket_k(const int* __restrict__ sid,
                         const int* __restrict__ mask,
                         int* __restrict__ counts,
                         int* __restrict__ bucket) {
    int i = blockIdx.x * blockDim.x + threadIdx.x;
    if (i >= NTOK) return;
    if (mask[i] != 0) {
        int e = sid[i];
        int slot = atomicAdd(&counts[e], 1);
        bucket[e * NTOK + slot] = i;
    }
}

// ---------------------------------------------------------------------------
// Kernel B: cls rows + MASKED token rows (table sums only) + attn flags.
// Unmasked token rows are written (fully) by proj_k.
// ---------------------------------------------------------------------------
__global__ void tables_k(const float* __restrict__ cls_content,
                         const float* __restrict__ pos_tab,
                         const float* __restrict__ id_tab,
                         const float* __restrict__ mod_tab,
                         const float* __restrict__ role_tab,
                         const int* __restrict__ pos,
                         const int* __restrict__ sid,
                         const int* __restrict__ mod,
                         const int* __restrict__ role,
                         const int* __restrict__ mask,
                         float* __restrict__ out,
                         float* __restrict__ attn) {
    int r = blockIdx.x;              // 0 .. B*ROWS-1
    int b = r / ROWS;
    int p = r % ROWS;
    int tid = threadIdx.x;
    float* orow = out + (size_t)r * M_;

    if (p == 0) {
#pragma unroll
        for (int j = 0; j < 3; ++j) {
            int m = tid + 256 * j;
            orow[m] = cls_content[m] + pos_tab[m] + id_tab[E_ * M_ + m];
        }
        if (tid == 0) attn[r] = 1.0f;
        return;
    }

    int idx = b * L_ + (p - 1);
    int mk = mask[idx];
    if (tid == 0) attn[r] = (mk != 0) ? 1.0f : 0.0f;
    if (mk != 0) return;             // proj_k writes this row

    const float* pr = pos_tab  + (size_t)pos[idx]  * M_;
    const float* ir = id_tab   + (size_t)sid[idx]  * M_;
    const float* mr = mod_tab  + (size_t)mod[idx]  * M_;
    const float* rr = role_tab + (size_t)role[idx] * M_;
#pragma unroll
    for (int j = 0; j < 3; ++j) {
        int m = tid + 256 * j;
        orow[m] = pr[m] + ir[m] + mr[m] + rr[m];
    }
}

// ---------------------------------------------------------------------------
// Kernel C: grouped expert projection, scalar-operand FMA version.
// 1-D grid of 768 blocks: id = g + 48*slot, g = chunk*16 + e  (g%8 == e%8 so
// all blocks of one expert land on one XCD -> W slice stays in that L2).
// Thread owns ONE m column; 16 tokens/tile; emb rows are WAVE-UNIFORM ->
// scalar loads (SGPR), no LDS at all. Epilogue writes FINAL rows
// (proj + bias + pos/id/mod/role tables) -> no RMW.
// ---------------------------------------------------------------------------
__launch_bounds__(256)
__global__ void proj_k(const float* __restrict__ emb,
                       const float* __restrict__ W,
                       const float* __restrict__ bias,
                       const float* __restrict__ pos_tab,
                       const float* __restrict__ id_tab,
                       const float* __restrict__ mod_tab,
                       const float* __restrict__ role_tab,
                       const int* __restrict__ pos,
                       const int* __restrict__ mod,
                       const int* __restrict__ role,
                       const int* __restrict__ counts,
                       const int* __restrict__ bucket,
                       float* __restrict__ out) {
    const int id    = blockIdx.x;
    const int g     = id % 48;
    const int slot  = id / 48;          // 0..15
    const int e     = g & 15;
    const int chunk = g >> 4;           // 0..2
    const int cnt   = counts[e];
    const int ntile = (cnt + 15) >> 4;
    const int tid   = threadIdx.x;
    const int m     = chunk * 256 + tid;

    const float* Wp  = W + (size_t)e * DIN * M_ + m;
    const float  bj  = bias[e * M_ + m];
    const float  idv = id_tab[(size_t)e * M_ + m];   // sid == e for this bucket

    for (int tile = slot; tile < ntile; tile += 16) {
        const int t0 = tile * 16;

        // Token ids: all-uniform addresses -> scalar loads, live in SGPRs.
        int ts[16];
#pragma unroll
        for (int i = 0; i < 16; ++i)
            ts[i] = (t0 + i < cnt) ? bucket[e * NTOK + t0 + i] : 0;

        float acc[16];
#pragma unroll
        for (int i = 0; i < 16; ++i) acc[i] = 0.0f;

        for (int d0 = 0; d0 < DIN; d0 += 8) {
            // W: per-lane coalesced vector loads (one dword per row, lanes
            // cover consecutive m).
            float w[8];
#pragma unroll
            for (int dd = 0; dd < 8; ++dd)
                w[dd] = Wp[(size_t)(d0 + dd) * M_];

            // emb: wave-uniform rows -> s_load_dwordx8; FMA takes the
            // scalar as src0 (1 SGPR operand per VALU instr = legal).
#pragma unroll
            for (int i = 0; i < 16; ++i) {
                const float* er = emb + (size_t)ts[i] * DIN + d0;
                float ev[8];
#pragma unroll
                for (int dd = 0; dd < 8; ++dd) ev[dd] = er[dd];
#pragma unroll
                for (int dd = 0; dd < 8; ++dd)
                    acc[i] = fmaf(ev[dd], w[dd], acc[i]);
            }
        }

        // Fused epilogue: final row = proj + bias + all four table rows.
#pragma unroll
        for (int i = 0; i < 16; ++i) {
            if (t0 + i < cnt) {
                int t  = ts[i];
                int bb = t >> 11;           // / L_
                int ll = t & (L_ - 1);
                float pv = pos_tab[(size_t)pos[t]  * M_ + m];
                float mv = mod_tab[(size_t)mod[t]  * M_ + m];
                float rv = role_tab[(size_t)role[t] * M_ + m];
                out[((size_t)bb * ROWS + ll + 1) * M_ + m] =
                    acc[i] + bj + idv + pv + mv + rv;
            }
        }
    }
}

// ---------------------------------------------------------------------------
extern "C" void kernel_launch(void* const* d_in, const int* in_sizes, int n_in,
                              void* d_out, int out_size, void* d_ws, size_t ws_size,
                              hipStream_t stream) {
    const float* emb      = (const float*)d_in[0];
    const float* W        = (const float*)d_in[1];
    const float* bias     = (const float*)d_in[2];
    const float* cls      = (const float*)d_in[3];
    const float* pos_tab  = (const float*)d_in[4];
    const float* id_tab   = (const float*)d_in[5];
    const float* mod_tab  = (const float*)d_in[6];
    const float* role_tab = (const float*)d_in[7];
    const int*   pos      = (const int*)d_in[8];
    const int*   sid      = (const int*)d_in[9];
    const int*   mod      = (const int*)d_in[10];
    const int*   role     = (const int*)d_in[11];
    const int*   mask     = (const int*)d_in[12];

    float* out  = (float*)d_out;
    float* attn = out + (size_t)B_ * ROWS * M_;

    int* counts = (int*)d_ws;
    int* bucket = counts + 16;

    hipMemsetAsync(d_ws, 0, 16 * sizeof(int), stream);

    bucket_k<<<(NTOK + 255) / 256, 256, 0, stream>>>(sid, mask, counts, bucket);

    tables_k<<<B_ * ROWS, 256, 0, stream>>>(cls, pos_tab, id_tab, mod_tab,
                                            role_tab, pos, sid, mod, role,
                                            mask, out, attn);

    proj_k<<<dim3(48 * 16), 256, 0, stream>>>(emb, W, bias, pos_tab, id_tab,
                                              mod_tab, role_tab, pos, mod, role,
                                              counts, bucket, out);
}

// Round 5
// 136.369 us; speedup vs baseline: 1.2544x; 1.2544x over previous
//
#include <hip/hip_runtime.h>

#define B_    4
#define L_    2048
#define DIN   256
#define E_    16
#define M_    768
#define ROWS  (L_ + 1)      // 2049 (cls + L)
#define NTOK  (B_ * L_)     // 8192

// ---------------------------------------------------------------------------
// Kernel A: bucket unmasked tokens by expert id.
// ws layout: int counts[16]; int bucket[16][NTOK]
// ---------------------------------------------------------------------------
__global__ void bucket_k(const int* __restrict__ sid,
                         const int* __restrict__ mask,
                         int* __restrict__ counts,
                         int* __restrict__ bucket) {
    int i = blockIdx.x * blockDim.x + threadIdx.x;
    if (i >= NTOK) return;
    if (mask[i] != 0) {
        int e = sid[i];
        int slot = atomicAdd(&counts[e], 1);
        bucket[e * NTOK + slot] = i;
    }
}

// ---------------------------------------------------------------------------
// Kernel B: cls rows + MASKED token rows (table sums only) + attn flags.
// Unmasked token rows are written (fully) by proj_k.
// ---------------------------------------------------------------------------
__global__ void tables_k(const float* __restrict__ cls_content,
                         const float* __restrict__ pos_tab,
                         const float* __restrict__ id_tab,
                         const float* __restrict__ mod_tab,
                         const float* __restrict__ role_tab,
                         const int* __restrict__ pos,
                         const int* __restrict__ sid,
                         const int* __restrict__ mod,
                         const int* __restrict__ role,
                         const int* __restrict__ mask,
                         float* __restrict__ out,
                         float* __restrict__ attn) {
    int r = blockIdx.x;              // 0 .. B*ROWS-1
    int b = r / ROWS;
    int p = r % ROWS;
    int tid = threadIdx.x;
    float* orow = out + (size_t)r * M_;

    if (p == 0) {
#pragma unroll
        for (int j = 0; j < 3; ++j) {
            int m = tid + 256 * j;
            orow[m] = cls_content[m] + pos_tab[m] + id_tab[E_ * M_ + m];
        }
        if (tid == 0) attn[r] = 1.0f;
        return;
    }

    int idx = b * L_ + (p - 1);
    int mk = mask[idx];
    if (tid == 0) attn[r] = (mk != 0) ? 1.0f : 0.0f;
    if (mk != 0) return;             // proj_k writes this row

    const float* pr = pos_tab  + (size_t)pos[idx]  * M_;
    const float* ir = id_tab   + (size_t)sid[idx]  * M_;
    const float* mr = mod_tab  + (size_t)mod[idx]  * M_;
    const float* rr = role_tab + (size_t)role[idx] * M_;
#pragma unroll
    for (int j = 0; j < 3; ++j) {
        int m = tid + 256 * j;
        orow[m] = pr[m] + ir[m] + mr[m] + rr[m];
    }
}

// ---------------------------------------------------------------------------
// Kernel C: grouped expert projection. LDS-broadcast emb, 3 cols/thread.
// Grid: id = slot*16 + e  (id%8 == e%8 -> one expert pinned to one XCD,
// W slice 768KB stays in that XCD's L2). 16 tokens/tile, grid-stride tiles.
// Thread owns m, m+256, m+512 -> 24 FMAs per 2 ds_read_b128 (VALU-bound).
// Epilogue writes FINAL rows (proj + bias + all tables) -> no RMW.
// ---------------------------------------------------------------------------
__launch_bounds__(256)
__global__ void proj_k(const float* __restrict__ emb,
                       const float* __restrict__ W,
                       const float* __restrict__ bias,
                       const float* __restrict__ pos_tab,
                       const float* __restrict__ id_tab,
                       const float* __restrict__ mod_tab,
                       const float* __restrict__ role_tab,
                       const int* __restrict__ pos,
                       const int* __restrict__ mod,
                       const int* __restrict__ role,
                       const int* __restrict__ counts,
                       const int* __restrict__ bucket,
                       float* __restrict__ out) {
    const int id   = blockIdx.x;
    const int e    = id & 15;           // id%8 == e%8 -> XCD pinning
    const int slot = id >> 4;           // 0..15
    const int cnt  = counts[e];
    const int ntile = (cnt + 15) >> 4;
    const int tid  = threadIdx.x;

    __shared__ float es[16][DIN];
    __shared__ int   ts[16];

    const float* Wp = W + (size_t)e * DIN * M_ + tid;
    float bj[3], idv[3];
#pragma unroll
    for (int j = 0; j < 3; ++j) {
        bj[j]  = bias[e * M_ + tid + 256 * j];
        idv[j] = id_tab[(size_t)e * M_ + tid + 256 * j];  // sid == e here
    }

    for (int tile = slot; tile < ntile; tile += 16) {
        const int t0 = tile * 16;

        __syncthreads();   // protect es/ts from previous iteration's readers
        if (tid < 16)
            ts[tid] = (t0 + tid < cnt) ? bucket[e * NTOK + t0 + tid] : 0;
        __syncthreads();
#pragma unroll
        for (int i = 0; i < 16; ++i)
            es[i][tid] = emb[(size_t)ts[i] * DIN + tid];
        __syncthreads();

        float acc[16][3];
#pragma unroll
        for (int i = 0; i < 16; ++i)
#pragma unroll
            for (int j = 0; j < 3; ++j) acc[i][j] = 0.0f;

        for (int d0 = 0; d0 < DIN; d0 += 8) {
            float w[8][3];
#pragma unroll
            for (int dd = 0; dd < 8; ++dd)
#pragma unroll
                for (int j = 0; j < 3; ++j)
                    w[dd][j] = Wp[(size_t)(d0 + dd) * M_ + 256 * j];

#pragma unroll
            for (int i = 0; i < 16; ++i) {
                float4 e0 = *reinterpret_cast<const float4*>(&es[i][d0]);
                float4 e1 = *reinterpret_cast<const float4*>(&es[i][d0 + 4]);
#pragma unroll
                for (int j = 0; j < 3; ++j) {
                    acc[i][j] = fmaf(e0.x, w[0][j], acc[i][j]);
                    acc[i][j] = fmaf(e0.y, w[1][j], acc[i][j]);
                    acc[i][j] = fmaf(e0.z, w[2][j], acc[i][j]);
                    acc[i][j] = fmaf(e0.w, w[3][j], acc[i][j]);
                    acc[i][j] = fmaf(e1.x, w[4][j], acc[i][j]);
                    acc[i][j] = fmaf(e1.y, w[5][j], acc[i][j]);
                    acc[i][j] = fmaf(e1.z, w[6][j], acc[i][j]);
                    acc[i][j] = fmaf(e1.w, w[7][j], acc[i][j]);
                }
            }
        }

        // Fused epilogue: final row = proj + bias + id/pos/mod/role tables.
#pragma unroll
        for (int i = 0; i < 16; ++i) {
            if (t0 + i < cnt) {
                int t  = ts[i];
                int bb = t >> 11;           // / L_
                int ll = t & (L_ - 1);
                float* orow = out + ((size_t)bb * ROWS + ll + 1) * M_;
                const float* pr = pos_tab  + (size_t)pos[t]  * M_;
                const float* mr = mod_tab  + (size_t)mod[t]  * M_;
                const float* rr = role_tab + (size_t)role[t] * M_;
#pragma unroll
                for (int j = 0; j < 3; ++j) {
                    int m = tid + 256 * j;
                    orow[m] = acc[i][j] + bj[j] + idv[j] + pr[m] + mr[m] + rr[m];
                }
            }
        }
    }
}

// ---------------------------------------------------------------------------
extern "C" void kernel_launch(void* const* d_in, const int* in_sizes, int n_in,
                              void* d_out, int out_size, void* d_ws, size_t ws_size,
                              hipStream_t stream) {
    const float* emb      = (const float*)d_in[0];
    const float* W        = (const float*)d_in[1];
    const float* bias     = (const float*)d_in[2];
    const float* cls      = (const float*)d_in[3];
    const float* pos_tab  = (const float*)d_in[4];
    const float* id_tab   = (const float*)d_in[5];
    const float* mod_tab  = (const float*)d_in[6];
    const float* role_tab = (const float*)d_in[7];
    const int*   pos      = (const int*)d_in[8];
    const int*   sid      = (const int*)d_in[9];
    const int*   mod      = (const int*)d_in[10];
    const int*   role     = (const int*)d_in[11];
    const int*   mask     = (const int*)d_in[12];

    float* out  = (float*)d_out;
    float* attn = out + (size_t)B_ * ROWS * M_;

    int* counts = (int*)d_ws;
    int* bucket = counts + 16;

    hipMemsetAsync(d_ws, 0, 16 * sizeof(int), stream);

    bucket_k<<<(NTOK + 255) / 256, 256, 0, stream>>>(sid, mask, counts, bucket);

    tables_k<<<B_ * ROWS, 256, 0, stream>>>(cls, pos_tab, id_tab, mod_tab,
                                            role_tab, pos, sid, mod, role,
                                            mask, out, attn);

    proj_k<<<dim3(256), 256, 0, stream>>>(emb, W, bias, pos_tab, id_tab,
                                          mod_tab, role_tab, pos, mod, role,
                                          counts, bucket, out);
}

// Round 6
// 73.238 us; speedup vs baseline: 2.3357x; 1.8620x over previous
//
#include <hip/hip_runtime.h>
#include <hip/hip_bf16.h>

#define B_    4
#define L_    2048
#define DIN   256
#define E_    16
#define M_    768
#define ROWS  (L_ + 1)      // 2049 (cls + L)
#define NTOK  (B_ * L_)     // 8192

typedef __attribute__((ext_vector_type(8))) short bf16x8;
typedef __attribute__((ext_vector_type(4))) float f32x4;

__device__ inline short f2bf(float f) {
    __hip_bfloat16 h = __float2bfloat16(f);
    return *reinterpret_cast<const short*>(&h);
}

// ---------------------------------------------------------------------------
// Kernel A: bucket unmasked tokens by expert id.
// ws layout: int counts[16]; int bucket[16][NTOK]
// ---------------------------------------------------------------------------
__global__ void bucket_k(const int* __restrict__ sid,
                         const int* __restrict__ mask,
                         int* __restrict__ counts,
                         int* __restrict__ bucket) {
    int i = blockIdx.x * blockDim.x + threadIdx.x;
    if (i >= NTOK) return;
    if (mask[i] != 0) {
        int e = sid[i];
        int slot = atomicAdd(&counts[e], 1);
        bucket[e * NTOK + slot] = i;
    }
}

// ---------------------------------------------------------------------------
// Kernel B: cls rows + MASKED token rows (table sums only) + attn flags.
// float4-vectorized: 192 threads, one float4 per thread. Unmasked rows are
// written (fully) by proj_k.
// ---------------------------------------------------------------------------
__global__ void tables_k(const float* __restrict__ cls_content,
                         const float* __restrict__ pos_tab,
                         const float* __restrict__ id_tab,
                         const float* __restrict__ mod_tab,
                         const float* __restrict__ role_tab,
                         const int* __restrict__ pos,
                         const int* __restrict__ sid,
                         const int* __restrict__ mod,
                         const int* __restrict__ role,
                         const int* __restrict__ mask,
                         float* __restrict__ out,
                         float* __restrict__ attn) {
    int r = blockIdx.x;              // 0 .. B*ROWS-1
    int b = r / ROWS;
    int p = r % ROWS;
    int tid = threadIdx.x;           // 0..191
    float4* orow = reinterpret_cast<float4*>(out + (size_t)r * M_);

    if (p == 0) {
        const float4* c4 = reinterpret_cast<const float4*>(cls_content);
        const float4* p4 = reinterpret_cast<const float4*>(pos_tab);
        const float4* i4 = reinterpret_cast<const float4*>(id_tab + (size_t)E_ * M_);
        float4 a = c4[tid], bb = p4[tid], c = i4[tid];
        orow[tid] = make_float4(a.x + bb.x + c.x, a.y + bb.y + c.y,
                                a.z + bb.z + c.z, a.w + bb.w + c.w);
        if (tid == 0) attn[r] = 1.0f;
        return;
    }

    int idx = b * L_ + (p - 1);
    int mk = mask[idx];
    if (tid == 0) attn[r] = (mk != 0) ? 1.0f : 0.0f;
    if (mk != 0) return;             // proj_k writes this row

    const float4* pr = reinterpret_cast<const float4*>(pos_tab  + (size_t)pos[idx]  * M_);
    const float4* ir = reinterpret_cast<const float4*>(id_tab   + (size_t)sid[idx]  * M_);
    const float4* mr = reinterpret_cast<const float4*>(mod_tab  + (size_t)mod[idx]  * M_);
    const float4* rr = reinterpret_cast<const float4*>(role_tab + (size_t)role[idx] * M_);
    float4 a = pr[tid], bb = ir[tid], c = mr[tid], d = rr[tid];
    orow[tid] = make_float4(a.x + bb.x + c.x + d.x, a.y + bb.y + c.y + d.y,
                            a.z + bb.z + c.z + d.z, a.w + bb.w + c.w + d.w);
}

// ---------------------------------------------------------------------------
// Kernel C: grouped expert projection via bf16 MFMA (16x16x32).
// Block = 256 thr = 4 waves; block tile = 32 tokens x 256 m-cols.
// Wave w owns n-range [chunk*256 + w*64, +64) = 4 n-frags x 2 m-halves.
// A-frag: lane l = emb[tok(l&15 + 16*mh)][k=(l>>4)*8+j]  (2x float4 + cvt)
// B-frag: lane l = W[e][k=(l>>4)*8+j][n0 + nt*16 + (l&15)] (8 strided dwords)
// D:      lane l = D[row=(l>>4)*4+r][col=l&15]   (m89-verified mapping)
// No LDS. Epilogue writes FINAL rows (acc + bias + all tables) -> no RMW.
// Grid (16,3,8): blockIdx.x = expert -> flat id%8 == e%8 -> XCD-pinned W.
// ---------------------------------------------------------------------------
__launch_bounds__(256)
__global__ void proj_k(const float* __restrict__ emb,
                       const float* __restrict__ W,
                       const float* __restrict__ bias,
                       const float* __restrict__ pos_tab,
                       const float* __restrict__ id_tab,
                       const float* __restrict__ mod_tab,
                       const float* __restrict__ role_tab,
                       const int* __restrict__ pos,
                       const int* __restrict__ mod,
                       const int* __restrict__ role,
                       const int* __restrict__ counts,
                       const int* __restrict__ bucket,
                       float* __restrict__ out) {
    const int e     = blockIdx.x;        // 0..15
    const int chunk = blockIdx.y;        // 0..2
    const int slot  = blockIdx.z;        // 0..7
    const int cnt   = counts[e];
    if (cnt == 0) return;
    const int ntile = (cnt + 31) >> 5;

    const int tid  = threadIdx.x;
    const int wid  = tid >> 6;           // 0..3
    const int lane = tid & 63;
    const int l15  = lane & 15;
    const int lg   = lane >> 4;          // 0..3

    const int n0 = chunk * 256 + wid * 64;
    const float* We = W + (size_t)e * DIN * M_;
    const int base = e * NTOK;

    // column-constant terms (uniform across tiles)
    float bv[4], iv[4];
#pragma unroll
    for (int nt = 0; nt < 4; ++nt) {
        int col = n0 + nt * 16 + l15;
        bv[nt] = bias[e * M_ + col];
        iv[nt] = id_tab[(size_t)e * M_ + col];   // sid == e in this bucket
    }

    for (int tile = slot; tile < ntile; tile += 8) {
        const int t0 = tile * 32;

        // token ids for this lane's A rows (2 m-halves), clamped at tail
        int tA[2];
#pragma unroll
        for (int mh = 0; mh < 2; ++mh) {
            int ridx = t0 + mh * 16 + l15;
            tA[mh] = bucket[base + min(ridx, cnt - 1)];
        }

        f32x4 acc[2][4];
#pragma unroll
        for (int mh = 0; mh < 2; ++mh)
#pragma unroll
            for (int nt = 0; nt < 4; ++nt)
                acc[mh][nt] = (f32x4){0.f, 0.f, 0.f, 0.f};

#pragma unroll 1
        for (int ks = 0; ks < 8; ++ks) {
            const int kl = ks * 32 + lg * 8;     // this lane's 8-k base

            bf16x8 aF[2];
#pragma unroll
            for (int mh = 0; mh < 2; ++mh) {
                const float* ap = emb + (size_t)tA[mh] * DIN + kl;
                f32x4 a0 = *reinterpret_cast<const f32x4*>(ap);
                f32x4 a1 = *reinterpret_cast<const f32x4*>(ap + 4);
#pragma unroll
                for (int j = 0; j < 4; ++j) {
                    aF[mh][j]     = f2bf(a0[j]);
                    aF[mh][4 + j] = f2bf(a1[j]);
                }
            }

#pragma unroll
            for (int nt = 0; nt < 4; ++nt) {
                const float* wp = We + (size_t)kl * M_ + n0 + nt * 16 + l15;
                float wv[8];
#pragma unroll
                for (int j = 0; j < 8; ++j) wv[j] = wp[(size_t)j * M_];
                bf16x8 bF;
#pragma unroll
                for (int j = 0; j < 8; ++j) bF[j] = f2bf(wv[j]);
                acc[0][nt] = __builtin_amdgcn_mfma_f32_16x16x32_bf16(aF[0], bF, acc[0][nt], 0, 0, 0);
                acc[1][nt] = __builtin_amdgcn_mfma_f32_16x16x32_bf16(aF[1], bF, acc[1][nt], 0, 0, 0);
            }
        }

        // Fused epilogue: final row = proj + bias + id/pos/mod/role tables.
#pragma unroll
        for (int mh = 0; mh < 2; ++mh) {
#pragma unroll
            for (int r = 0; r < 4; ++r) {
                int ridx = t0 + mh * 16 + lg * 4 + r;
                bool ok  = ridx < cnt;
                int t    = bucket[base + min(ridx, cnt - 1)];
                int bb   = t >> 11;               // / L_
                int ll   = t & (L_ - 1);
                float* orow = out + ((size_t)bb * ROWS + ll + 1) * M_;
                const float* pr = pos_tab  + (size_t)pos[t]  * M_;
                const float* mr = mod_tab  + (size_t)mod[t]  * M_;
                const float* rr = role_tab + (size_t)role[t] * M_;
                if (ok) {
#pragma unroll
                    for (int nt = 0; nt < 4; ++nt) {
                        int col = n0 + nt * 16 + l15;
                        orow[col] = acc[mh][nt][r] + bv[nt] + iv[nt]
                                  + pr[col] + mr[col] + rr[col];
                    }
                }
            }
        }
    }
}

// ---------------------------------------------------------------------------
extern "C" void kernel_launch(void* const* d_in, const int* in_sizes, int n_in,
                              void* d_out, int out_size, void* d_ws, size_t ws_size,
                              hipStream_t stream) {
    const float* emb      = (const float*)d_in[0];
    const float* W        = (const float*)d_in[1];
    const float* bias     = (const float*)d_in[2];
    const float* cls      = (const float*)d_in[3];
    const float* pos_tab  = (const float*)d_in[4];
    const float* id_tab   = (const float*)d_in[5];
    const float* mod_tab  = (const float*)d_in[6];
    const float* role_tab = (const float*)d_in[7];
    const int*   pos      = (const int*)d_in[8];
    const int*   sid      = (const int*)d_in[9];
    const int*   mod      = (const int*)d_in[10];
    const int*   role     = (const int*)d_in[11];
    const int*   mask     = (const int*)d_in[12];

    float* out  = (float*)d_out;
    float* attn = out + (size_t)B_ * ROWS * M_;

    int* counts = (int*)d_ws;
    int* bucket = counts + 16;

    hipMemsetAsync(d_ws, 0, 16 * sizeof(int), stream);

    bucket_k<<<(NTOK + 255) / 256, 256, 0, stream>>>(sid, mask, counts, bucket);

    tables_k<<<B_ * ROWS, 192, 0, stream>>>(cls, pos_tab, id_tab, mod_tab,
                                            role_tab, pos, sid, mod, role,
                                            mask, out, attn);

    proj_k<<<dim3(16, 3, 8), 256, 0, stream>>>(emb, W, bias, pos_tab, id_tab,
                                               mod_tab, role_tab, pos, mod, role,
                                               counts, bucket, out);
}

// Round 7
// 52.576 us; speedup vs baseline: 3.2536x; 1.3930x over previous
//
#include <hip/hip_runtime.h>
#include <hip/hip_bf16.h>

#define B_    4
#define L_    2048
#define DIN   256
#define E_    16
#define M_    768
#define ROWS  (L_ + 1)      // 2049
#define NTOK  (B_ * L_)     // 8192
#define K8    (DIN / 8)     // 32

typedef __attribute__((ext_vector_type(8))) short bf16x8;
typedef __attribute__((ext_vector_type(4))) float f32x4;

__device__ inline short f2bf(float f) {
    __hip_bfloat16 h = __float2bfloat16(f);
    return *reinterpret_cast<const short*>(&h);
}

// ---------------------------------------------------------------------------
// prep_k: fused {bucket, pack W->bf16 [e][k8][n][8], pack emb->bf16 [tok][k]}.
// Section A (32 blocks): bucket unmasked tokens by expert.
// Section B (1536 blocks): Wb[(e*32+k8)*768 + n][8] = bf16(W[e][k8*8+j][n])
//   reads coalesced along n, writes 16B/thread contiguous.
// Section C (1024 blocks): embb[tok*256 + k8*8 + j] = bf16(emb[...])
//   fully coalesced both sides.
// ---------------------------------------------------------------------------
#define BK_BLOCKS (NTOK / 256)            // 32
#define PW_BLOCKS ((E_ * K8 * M_) / 256)  // 1536
#define PE_BLOCKS ((NTOK * K8) / 256)     // 1024

__global__ void prep_k(const float* __restrict__ emb,
                       const float* __restrict__ W,
                       const int* __restrict__ sid,
                       const int* __restrict__ mask,
                       int* __restrict__ counts,
                       int* __restrict__ bucket,
                       short* __restrict__ Wb,
                       short* __restrict__ embb) {
    int bid = blockIdx.x, tid = threadIdx.x;

    if (bid < BK_BLOCKS) {
        int i = bid * 256 + tid;
        if (mask[i] != 0) {
            int e = sid[i];
            int slot = atomicAdd(&counts[e], 1);
            bucket[e * NTOK + slot] = i;
        }
        return;
    }
    bid -= BK_BLOCKS;

    if (bid < PW_BLOCKS) {
        int u   = bid * 256 + tid;       // (e*32+k8)*768 + n
        int n   = u % M_;
        int ek8 = u / M_;
        const float* src = W + (size_t)ek8 * 8 * M_ + n;
        bf16x8 v;
#pragma unroll
        for (int j = 0; j < 8; ++j) v[j] = f2bf(src[(size_t)j * M_]);
        *reinterpret_cast<bf16x8*>(Wb + (size_t)u * 8) = v;
        return;
    }
    bid -= PW_BLOCKS;

    {
        int u = bid * 256 + tid;         // tok*32 + k8
        const float* src = emb + (size_t)u * 8;
        f32x4 a0 = *reinterpret_cast<const f32x4*>(src);
        f32x4 a1 = *reinterpret_cast<const f32x4*>(src + 4);
        bf16x8 v;
#pragma unroll
        for (int j = 0; j < 4; ++j) { v[j] = f2bf(a0[j]); v[4 + j] = f2bf(a1[j]); }
        *reinterpret_cast<bf16x8*>(embb + (size_t)u * 8) = v;
    }
}

// ---------------------------------------------------------------------------
// tables_k: cls rows + MASKED token rows + attn flags. 4 rows per block,
// 192 threads (one float4 per thread per row).
// ---------------------------------------------------------------------------
__global__ void tables_k(const float* __restrict__ cls_content,
                         const float* __restrict__ pos_tab,
                         const float* __restrict__ id_tab,
                         const float* __restrict__ mod_tab,
                         const float* __restrict__ role_tab,
                         const int* __restrict__ pos,
                         const int* __restrict__ sid,
                         const int* __restrict__ mod,
                         const int* __restrict__ role,
                         const int* __restrict__ mask,
                         float* __restrict__ out,
                         float* __restrict__ attn) {
    int tid = threadIdx.x;               // 0..191
#pragma unroll
    for (int rr = 0; rr < 4; ++rr) {
        int r = blockIdx.x * 4 + rr;     // 0 .. B*ROWS-1 (8196 = 2049*4)
        int b = r / ROWS;
        int p = r % ROWS;
        float4* orow = reinterpret_cast<float4*>(out + (size_t)r * M_);

        if (p == 0) {
            const float4* c4 = reinterpret_cast<const float4*>(cls_content);
            const float4* p4 = reinterpret_cast<const float4*>(pos_tab);
            const float4* i4 = reinterpret_cast<const float4*>(id_tab + (size_t)E_ * M_);
            float4 a = c4[tid], bb = p4[tid], c = i4[tid];
            orow[tid] = make_float4(a.x + bb.x + c.x, a.y + bb.y + c.y,
                                    a.z + bb.z + c.z, a.w + bb.w + c.w);
            if (tid == 0) attn[r] = 1.0f;
            continue;
        }

        int idx = b * L_ + (p - 1);
        int mk = mask[idx];
        if (tid == 0) attn[r] = (mk != 0) ? 1.0f : 0.0f;
        if (mk != 0) continue;           // proj_k writes this row

        const float4* pr = reinterpret_cast<const float4*>(pos_tab  + (size_t)pos[idx]  * M_);
        const float4* ir = reinterpret_cast<const float4*>(id_tab   + (size_t)sid[idx]  * M_);
        const float4* mr = reinterpret_cast<const float4*>(mod_tab  + (size_t)mod[idx]  * M_);
        const float4* rr2 = reinterpret_cast<const float4*>(role_tab + (size_t)role[idx] * M_);
        float4 a = pr[tid], bb = ir[tid], c = mr[tid], d = rr2[tid];
        orow[tid] = make_float4(a.x + bb.x + c.x + d.x, a.y + bb.y + c.y + d.y,
                                a.z + bb.z + c.z + d.z, a.w + bb.w + c.w + d.w);
    }
}

// ---------------------------------------------------------------------------
// proj_k: grouped expert projection via bf16 MFMA on PRE-PACKED operands.
// Block = 256 thr = 4 waves; tile = 16 tokens x 256 m-cols (wave: 4 n-frags).
// A-frag: one bf16x8 load from embb (lane rows 16B-gather, 64B/row/wave).
// B-frag: one bf16x8 load from Wb (16 lanes x 16B = 256B contiguous).
// D: col=lane&15, row=(lane>>4)*4+r (m89-verified). Epilogue writes FINAL
// rows (acc + bias + id/pos/mod/role) -> no RMW.
// Grid (16,3,16): flat id % 8 == e % 8 -> expert's Wb pinned to one XCD L2.
// ---------------------------------------------------------------------------
__launch_bounds__(256)
__global__ void proj_k(const short* __restrict__ embb,
                       const short* __restrict__ Wb,
                       const float* __restrict__ bias,
                       const float* __restrict__ pos_tab,
                       const float* __restrict__ id_tab,
                       const float* __restrict__ mod_tab,
                       const float* __restrict__ role_tab,
                       const int* __restrict__ pos,
                       const int* __restrict__ mod,
                       const int* __restrict__ role,
                       const int* __restrict__ counts,
                       const int* __restrict__ bucket,
                       float* __restrict__ out) {
    const int e     = blockIdx.x;        // 0..15
    const int chunk = blockIdx.y;        // 0..2
    const int slot  = blockIdx.z;        // 0..15
    const int cnt   = counts[e];
    if (cnt == 0) return;
    const int ntile = (cnt + 15) >> 4;

    const int tid  = threadIdx.x;
    const int wid  = tid >> 6;
    const int lane = tid & 63;
    const int l15  = lane & 15;
    const int lg   = lane >> 4;

    const int n0   = chunk * 256 + wid * 64;
    const int base = e * NTOK;

    float bv[4], iv[4];
#pragma unroll
    for (int nt = 0; nt < 4; ++nt) {
        int col = n0 + nt * 16 + l15;
        bv[nt] = bias[e * M_ + col];
        iv[nt] = id_tab[(size_t)e * M_ + col];   // sid == e in this bucket
    }

    for (int tile = slot; tile < ntile; tile += 16) {
        const int t0 = tile * 16;
        const int tA = bucket[base + min(t0 + l15, cnt - 1)];
        const bf16x8* arow = reinterpret_cast<const bf16x8*>(embb + (size_t)tA * DIN);

        f32x4 acc[4];
#pragma unroll
        for (int nt = 0; nt < 4; ++nt) acc[nt] = (f32x4){0.f, 0.f, 0.f, 0.f};

#pragma unroll
        for (int ks = 0; ks < 8; ++ks) {
            bf16x8 aF = arow[ks * 4 + lg];
            const bf16x8* bp = reinterpret_cast<const bf16x8*>(
                Wb + ((size_t)(e * K8 + ks * 4 + lg) * M_ + n0) * 8);
#pragma unroll
            for (int nt = 0; nt < 4; ++nt) {
                bf16x8 bF = bp[nt * 16 + l15];
                acc[nt] = __builtin_amdgcn_mfma_f32_16x16x32_bf16(aF, bF, acc[nt], 0, 0, 0);
            }
        }

        // Fused epilogue: final row = proj + bias + id/pos/mod/role tables.
#pragma unroll
        for (int r = 0; r < 4; ++r) {
            int ridx = t0 + lg * 4 + r;
            if (ridx < cnt) {
                int t  = bucket[base + ridx];
                int bb = t >> 11;            // / L_
                int ll = t & (L_ - 1);
                float* orow = out + ((size_t)bb * ROWS + ll + 1) * M_;
                const float* pr = pos_tab  + (size_t)pos[t]  * M_;
                const float* mr = mod_tab  + (size_t)mod[t]  * M_;
                const float* rr = role_tab + (size_t)role[t] * M_;
#pragma unroll
                for (int nt = 0; nt < 4; ++nt) {
                    int col = n0 + nt * 16 + l15;
                    orow[col] = acc[nt][r] + bv[nt] + iv[nt]
                              + pr[col] + mr[col] + rr[col];
                }
            }
        }
    }
}

// ---------------------------------------------------------------------------
// Fallback (ws too small for packing): round-5 kernels, known-good at 73us.
// ---------------------------------------------------------------------------
__global__ void bucket_k(const int* __restrict__ sid,
                         const int* __restrict__ mask,
                         int* __restrict__ counts,
                         int* __restrict__ bucket) {
    int i = blockIdx.x * blockDim.x + threadIdx.x;
    if (i >= NTOK) return;
    if (mask[i] != 0) {
        int e = sid[i];
        int slot = atomicAdd(&counts[e], 1);
        bucket[e * NTOK + slot] = i;
    }
}

__launch_bounds__(256)
__global__ void proj5_k(const float* __restrict__ emb,
                        const float* __restrict__ W,
                        const float* __restrict__ bias,
                        const float* __restrict__ pos_tab,
                        const float* __restrict__ id_tab,
                        const float* __restrict__ mod_tab,
                        const float* __restrict__ role_tab,
                        const int* __restrict__ pos,
                        const int* __restrict__ mod,
                        const int* __restrict__ role,
                        const int* __restrict__ counts,
                        const int* __restrict__ bucket,
                        float* __restrict__ out) {
    const int e     = blockIdx.x;
    const int chunk = blockIdx.y;
    const int slot  = blockIdx.z;
    const int cnt   = counts[e];
    if (cnt == 0) return;
    const int ntile = (cnt + 31) >> 5;
    const int tid = threadIdx.x, wid = tid >> 6, lane = tid & 63;
    const int l15 = lane & 15, lg = lane >> 4;
    const int n0 = chunk * 256 + wid * 64;
    const float* We = W + (size_t)e * DIN * M_;
    const int base = e * NTOK;

    float bv[4], iv[4];
#pragma unroll
    for (int nt = 0; nt < 4; ++nt) {
        int col = n0 + nt * 16 + l15;
        bv[nt] = bias[e * M_ + col];
        iv[nt] = id_tab[(size_t)e * M_ + col];
    }

    for (int tile = slot; tile < ntile; tile += 8) {
        const int t0 = tile * 32;
        int tA[2];
#pragma unroll
        for (int mh = 0; mh < 2; ++mh)
            tA[mh] = bucket[base + min(t0 + mh * 16 + l15, cnt - 1)];

        f32x4 acc[2][4];
#pragma unroll
        for (int mh = 0; mh < 2; ++mh)
#pragma unroll
            for (int nt = 0; nt < 4; ++nt) acc[mh][nt] = (f32x4){0.f,0.f,0.f,0.f};

#pragma unroll 1
        for (int ks = 0; ks < 8; ++ks) {
            const int kl = ks * 32 + lg * 8;
            bf16x8 aF[2];
#pragma unroll
            for (int mh = 0; mh < 2; ++mh) {
                const float* ap = emb + (size_t)tA[mh] * DIN + kl;
                f32x4 a0 = *reinterpret_cast<const f32x4*>(ap);
                f32x4 a1 = *reinterpret_cast<const f32x4*>(ap + 4);
#pragma unroll
                for (int j = 0; j < 4; ++j) { aF[mh][j] = f2bf(a0[j]); aF[mh][4+j] = f2bf(a1[j]); }
            }
#pragma unroll
            for (int nt = 0; nt < 4; ++nt) {
                const float* wp = We + (size_t)kl * M_ + n0 + nt * 16 + l15;
                bf16x8 bF;
#pragma unroll
                for (int j = 0; j < 8; ++j) bF[j] = f2bf(wp[(size_t)j * M_]);
                acc[0][nt] = __builtin_amdgcn_mfma_f32_16x16x32_bf16(aF[0], bF, acc[0][nt], 0, 0, 0);
                acc[1][nt] = __builtin_amdgcn_mfma_f32_16x16x32_bf16(aF[1], bF, acc[1][nt], 0, 0, 0);
            }
        }
#pragma unroll
        for (int mh = 0; mh < 2; ++mh)
#pragma unroll
            for (int r = 0; r < 4; ++r) {
                int ridx = t0 + mh * 16 + lg * 4 + r;
                if (ridx < cnt) {
                    int t = bucket[base + ridx];
                    int bb = t >> 11, ll = t & (L_ - 1);
                    float* orow = out + ((size_t)bb * ROWS + ll + 1) * M_;
                    const float* pr = pos_tab  + (size_t)pos[t]  * M_;
                    const float* mr = mod_tab  + (size_t)mod[t]  * M_;
                    const float* rr = role_tab + (size_t)role[t] * M_;
#pragma unroll
                    for (int nt = 0; nt < 4; ++nt) {
                        int col = n0 + nt * 16 + l15;
                        orow[col] = acc[mh][nt][r] + bv[nt] + iv[nt]
                                  + pr[col] + mr[col] + rr[col];
                    }
                }
            }
    }
}

// ---------------------------------------------------------------------------
extern "C" void kernel_launch(void* const* d_in, const int* in_sizes, int n_in,
                              void* d_out, int out_size, void* d_ws, size_t ws_size,
                              hipStream_t stream) {
    const float* emb      = (const float*)d_in[0];
    const float* W        = (const float*)d_in[1];
    const float* bias     = (const float*)d_in[2];
    const float* cls      = (const float*)d_in[3];
    const float* pos_tab  = (const float*)d_in[4];
    const float* id_tab   = (const float*)d_in[5];
    const float* mod_tab  = (const float*)d_in[6];
    const float* role_tab = (const float*)d_in[7];
    const int*   pos      = (const int*)d_in[8];
    const int*   sid      = (const int*)d_in[9];
    const int*   mod      = (const int*)d_in[10];
    const int*   role     = (const int*)d_in[11];
    const int*   mask     = (const int*)d_in[12];

    float* out  = (float*)d_out;
    float* attn = out + (size_t)B_ * ROWS * M_;

    // ws layout: counts[16] (64B) | bucket[16][NTOK] (512KB) | Wb bf16 | embb bf16
    int*   counts = (int*)d_ws;
    int*   bucket = counts + 16;
    short* Wb     = (short*)((char*)d_ws + 64 + (size_t)E_ * NTOK * 4);
    short* embb   = Wb + (size_t)E_ * DIN * M_;
    const size_t NEED = 64 + (size_t)E_ * NTOK * 4
                      + (size_t)E_ * DIN * M_ * 2 + (size_t)NTOK * DIN * 2;

    hipMemsetAsync(d_ws, 0, 64, stream);

    if (ws_size >= NEED) {
        prep_k<<<BK_BLOCKS + PW_BLOCKS + PE_BLOCKS, 256, 0, stream>>>(
            emb, W, sid, mask, counts, bucket, Wb, embb);

        tables_k<<<(B_ * ROWS) / 4, 192, 0, stream>>>(
            cls, pos_tab, id_tab, mod_tab, role_tab,
            pos, sid, mod, role, mask, out, attn);

        proj_k<<<dim3(16, 3, 16), 256, 0, stream>>>(
            embb, Wb, bias, pos_tab, id_tab, mod_tab, role_tab,
            pos, mod, role, counts, bucket, out);
    } else {
        bucket_k<<<(NTOK + 255) / 256, 256, 0, stream>>>(sid, mask, counts, bucket);

        tables_k<<<(B_ * ROWS) / 4, 192, 0, stream>>>(
            cls, pos_tab, id_tab, mod_tab, role_tab,
            pos, sid, mod, role, mask, out, attn);

        proj5_k<<<dim3(16, 3, 8), 256, 0, stream>>>(
            emb, W, bias, pos_tab, id_tab, mod_tab, role_tab,
            pos, mod, role, counts, bucket, out);
    }
}

// Round 8
// 51.143 us; speedup vs baseline: 3.3448x; 1.0280x over previous
//
#include <hip/hip_runtime.h>
#include <hip/hip_bf16.h>

#define B_    4
#define L_    2048
#define DIN   256
#define E_    16
#define M_    768
#define ROWS  (L_ + 1)      // 2049
#define NTOK  (B_ * L_)     // 8192
#define K8    (DIN / 8)     // 32

typedef __attribute__((ext_vector_type(8))) short bf16x8;
typedef __attribute__((ext_vector_type(4))) float f32x4;

__device__ inline short f2bf(float f) {
    __hip_bfloat16 h = __float2bfloat16(f);
    return *reinterpret_cast<const short*>(&h);
}

// ---------------------------------------------------------------------------
// prep_k: ONE dispatch doing 4 independent jobs, selected by blockIdx.x:
//   [0,16)        bucket: block e scans sid/mask, LDS prefix-scan -> stable
//                 bucket list + counts[e]. No atomics, no pre-zeroing.
//   [16,1552)     pack W -> bf16 Wb[(e*32+k8)*768 + n][8]
//   [1552,2576)   pack emb -> bf16 embb[tok][k]
//   [2576,4625)   tables: cls rows + MASKED token rows + attn flags
//                 (4 rows/block, 192 active threads, float4)
// All sections write disjoint memory; order within kernel irrelevant.
// ---------------------------------------------------------------------------
#define SB 16
#define SW ((E_ * K8 * M_) / 256)        // 1536
#define SE ((NTOK * K8) / 256)           // 1024
#define ST ((B_ * ROWS) / 4)             // 2049

__launch_bounds__(256)
__global__ void prep_k(const float* __restrict__ emb,
                       const float* __restrict__ W,
                       const float* __restrict__ cls_content,
                       const float* __restrict__ pos_tab,
                       const float* __restrict__ id_tab,
                       const float* __restrict__ mod_tab,
                       const float* __restrict__ role_tab,
                       const int* __restrict__ pos,
                       const int* __restrict__ sid,
                       const int* __restrict__ mod,
                       const int* __restrict__ role,
                       const int* __restrict__ mask,
                       int* __restrict__ counts,
                       int* __restrict__ bucket,
                       short* __restrict__ Wb,
                       short* __restrict__ embb,
                       float* __restrict__ out,
                       float* __restrict__ attn) {
    int bid = blockIdx.x, tid = threadIdx.x;

    // ---- Section A: deterministic bucket via block prefix-scan ----
    if (bid < SB) {
        const int e = bid;
        __shared__ int s[256];
        const int base = tid * 32;
        int lc = 0;
#pragma unroll 8
        for (int j = 0; j < 32; ++j) {
            int i = base + j;
            lc += (mask[i] != 0 && sid[i] == e) ? 1 : 0;
        }
        s[tid] = lc;
        __syncthreads();
        // Hillis-Steele inclusive scan
        for (int off = 1; off < 256; off <<= 1) {
            int v = (tid >= off) ? s[tid - off] : 0;
            __syncthreads();
            s[tid] += v;
            __syncthreads();
        }
        int w = s[tid] - lc;                  // exclusive prefix
        if (tid == 255) counts[e] = s[255];
#pragma unroll 8
        for (int j = 0; j < 32; ++j) {
            int i = base + j;
            if (mask[i] != 0 && sid[i] == e) bucket[e * NTOK + (w++)] = i;
        }
        return;
    }
    bid -= SB;

    // ---- Section B: pack W -> bf16, k-inner-8 layout ----
    if (bid < SW) {
        int u   = bid * 256 + tid;            // (e*32+k8)*768 + n
        int n   = u % M_;
        int ek8 = u / M_;
        const float* src = W + (size_t)ek8 * 8 * M_ + n;
        bf16x8 v;
#pragma unroll
        for (int j = 0; j < 8; ++j) v[j] = f2bf(src[(size_t)j * M_]);
        *reinterpret_cast<bf16x8*>(Wb + (size_t)u * 8) = v;
        return;
    }
    bid -= SW;

    // ---- Section C: pack emb -> bf16 ----
    if (bid < SE) {
        int u = bid * 256 + tid;              // tok*32 + k8
        const float* src = emb + (size_t)u * 8;
        f32x4 a0 = *reinterpret_cast<const f32x4*>(src);
        f32x4 a1 = *reinterpret_cast<const f32x4*>(src + 4);
        bf16x8 v;
#pragma unroll
        for (int j = 0; j < 4; ++j) { v[j] = f2bf(a0[j]); v[4 + j] = f2bf(a1[j]); }
        *reinterpret_cast<bf16x8*>(embb + (size_t)u * 8) = v;
        return;
    }
    bid -= SW ? 0 : 0;
    bid -= SE;

    // ---- Section D: tables (cls + masked rows + attn), 4 rows/block ----
    if (tid >= 192) return;
#pragma unroll
    for (int rr = 0; rr < 4; ++rr) {
        int r = bid * 4 + rr;                 // 0 .. 8195
        int b = r / ROWS;
        int p = r % ROWS;
        float4* orow = reinterpret_cast<float4*>(out + (size_t)r * M_);

        if (p == 0) {
            const float4* c4 = reinterpret_cast<const float4*>(cls_content);
            const float4* p4 = reinterpret_cast<const float4*>(pos_tab);
            const float4* i4 = reinterpret_cast<const float4*>(id_tab + (size_t)E_ * M_);
            float4 a = c4[tid], bb = p4[tid], c = i4[tid];
            orow[tid] = make_float4(a.x + bb.x + c.x, a.y + bb.y + c.y,
                                    a.z + bb.z + c.z, a.w + bb.w + c.w);
            if (tid == 0) attn[r] = 1.0f;
            continue;
        }

        int idx = b * L_ + (p - 1);
        int mk = mask[idx];
        if (tid == 0) attn[r] = (mk != 0) ? 1.0f : 0.0f;
        if (mk != 0) continue;                // proj_k writes this row

        const float4* pr = reinterpret_cast<const float4*>(pos_tab  + (size_t)pos[idx]  * M_);
        const float4* ir = reinterpret_cast<const float4*>(id_tab   + (size_t)sid[idx]  * M_);
        const float4* mr = reinterpret_cast<const float4*>(mod_tab  + (size_t)mod[idx]  * M_);
        const float4* rt = reinterpret_cast<const float4*>(role_tab + (size_t)role[idx] * M_);
        float4 a = pr[tid], bb = ir[tid], c = mr[tid], d = rt[tid];
        orow[tid] = make_float4(a.x + bb.x + c.x + d.x, a.y + bb.y + c.y + d.y,
                                a.z + bb.z + c.z + d.z, a.w + bb.w + c.w + d.w);
    }
}

// ---------------------------------------------------------------------------
// proj_k: grouped expert projection via bf16 MFMA on pre-packed operands.
// Block = 256 thr = 4 waves; tile = 16 tokens x 256 m-cols (wave: 4 n-frags).
// All 8 A-frags preloaded (deep MLP), then 8 ks x {4 B loads + 4 MFMA}.
// D mapping: col=lane&15, row=(lane>>4)*4+r (m89-verified).
// Epilogue writes FINAL rows (acc + bias + id/pos/mod/role) -> no RMW.
// Grid (16,3,16): flat id % 8 == e % 8 -> expert's Wb pinned to one XCD L2.
// ---------------------------------------------------------------------------
__launch_bounds__(256)
__global__ void proj_k(const short* __restrict__ embb,
                       const short* __restrict__ Wb,
                       const float* __restrict__ bias,
                       const float* __restrict__ pos_tab,
                       const float* __restrict__ id_tab,
                       const float* __restrict__ mod_tab,
                       const float* __restrict__ role_tab,
                       const int* __restrict__ pos,
                       const int* __restrict__ mod,
                       const int* __restrict__ role,
                       const int* __restrict__ counts,
                       const int* __restrict__ bucket,
                       float* __restrict__ out) {
    const int e     = blockIdx.x;        // 0..15
    const int chunk = blockIdx.y;        // 0..2
    const int slot  = blockIdx.z;        // 0..15
    const int cnt   = counts[e];
    if (cnt == 0) return;
    const int ntile = (cnt + 15) >> 4;

    const int tid  = threadIdx.x;
    const int wid  = tid >> 6;
    const int lane = tid & 63;
    const int l15  = lane & 15;
    const int lg   = lane >> 4;

    const int n0   = chunk * 256 + wid * 64;
    const int base = e * NTOK;

    float bv[4], iv[4];
#pragma unroll
    for (int nt = 0; nt < 4; ++nt) {
        int col = n0 + nt * 16 + l15;
        bv[nt] = bias[e * M_ + col];
        iv[nt] = id_tab[(size_t)e * M_ + col];   // sid == e in this bucket
    }

    for (int tile = slot; tile < ntile; tile += 16) {
        const int t0 = tile * 16;
        const int tA = bucket[base + min(t0 + l15, cnt - 1)];
        const bf16x8* arow = reinterpret_cast<const bf16x8*>(embb + (size_t)tA * DIN);

        // Preload ALL A-frags: 8 independent dwordx4 in flight.
        bf16x8 aF[8];
#pragma unroll
        for (int ks = 0; ks < 8; ++ks) aF[ks] = arow[ks * 4 + lg];

        f32x4 acc[4];
#pragma unroll
        for (int nt = 0; nt < 4; ++nt) acc[nt] = (f32x4){0.f, 0.f, 0.f, 0.f};

#pragma unroll
        for (int ks = 0; ks < 8; ++ks) {
            const bf16x8* bp = reinterpret_cast<const bf16x8*>(
                Wb + ((size_t)(e * K8 + ks * 4 + lg) * M_ + n0) * 8);
#pragma unroll
            for (int nt = 0; nt < 4; ++nt) {
                bf16x8 bF = bp[nt * 16 + l15];
                acc[nt] = __builtin_amdgcn_mfma_f32_16x16x32_bf16(aF[ks], bF, acc[nt], 0, 0, 0);
            }
        }

        // Fused epilogue: final row = proj + bias + id/pos/mod/role tables.
#pragma unroll
        for (int r = 0; r < 4; ++r) {
            int ridx = t0 + lg * 4 + r;
            if (ridx < cnt) {
                int t  = bucket[base + ridx];
                int bb = t >> 11;            // / L_
                int ll = t & (L_ - 1);
                float* orow = out + ((size_t)bb * ROWS + ll + 1) * M_;
                const float* pr = pos_tab  + (size_t)pos[t]  * M_;
                const float* mr = mod_tab  + (size_t)mod[t]  * M_;
                const float* rt = role_tab + (size_t)role[t] * M_;
#pragma unroll
                for (int nt = 0; nt < 4; ++nt) {
                    int col = n0 + nt * 16 + l15;
                    orow[col] = acc[nt][r] + bv[nt] + iv[nt]
                              + pr[col] + mr[col] + rt[col];
                }
            }
        }
    }
}

// ---------------------------------------------------------------------------
extern "C" void kernel_launch(void* const* d_in, const int* in_sizes, int n_in,
                              void* d_out, int out_size, void* d_ws, size_t ws_size,
                              hipStream_t stream) {
    const float* emb      = (const float*)d_in[0];
    const float* W        = (const float*)d_in[1];
    const float* bias     = (const float*)d_in[2];
    const float* cls      = (const float*)d_in[3];
    const float* pos_tab  = (const float*)d_in[4];
    const float* id_tab   = (const float*)d_in[5];
    const float* mod_tab  = (const float*)d_in[6];
    const float* role_tab = (const float*)d_in[7];
    const int*   pos      = (const int*)d_in[8];
    const int*   sid      = (const int*)d_in[9];
    const int*   mod      = (const int*)d_in[10];
    const int*   role     = (const int*)d_in[11];
    const int*   mask     = (const int*)d_in[12];

    float* out  = (float*)d_out;
    float* attn = out + (size_t)B_ * ROWS * M_;

    // ws layout: counts[16] (64B) | bucket[16][NTOK] (512KB) | Wb | embb
    int*   counts = (int*)d_ws;
    int*   bucket = counts + 16;
    short* Wb     = (short*)((char*)d_ws + 64 + (size_t)E_ * NTOK * 4);
    short* embb   = Wb + (size_t)E_ * DIN * M_;

    prep_k<<<SB + SW + SE + ST, 256, 0, stream>>>(
        emb, W, cls, pos_tab, id_tab, mod_tab, role_tab,
        pos, sid, mod, role, mask,
        counts, bucket, Wb, embb, out, attn);

    proj_k<<<dim3(16, 3, 16), 256, 0, stream>>>(
        embb, Wb, bias, pos_tab, id_tab, mod_tab, role_tab,
        pos, mod, role, counts, bucket, out);
}